// Round 5
// baseline (319.186 us; speedup 1.0000x reference)
//
#include <hip/hip_runtime.h>
#include <hip/hip_bf16.h>
#include <math.h>

typedef __bf16 bf16_t;
typedef __attribute__((ext_vector_type(8))) __bf16 bf16x8;
typedef __attribute__((ext_vector_type(4))) float f32x4;

#define GAS __attribute__((address_space(1)))
#define LAS __attribute__((address_space(3)))

#define BB 2
#define TT 1024
#define CC 2048
#define HH 6
#define KK 128
#define VV 256
#define KD 768
#define VD 1536
#define NQKV 3072
#define NCAT 4608
#define NC 16     // chunks per sequence
#define CL 64     // chunk length

__device__ __forceinline__ void gload_lds16(const void* g, void* l) {
  __builtin_amdgcn_global_load_lds((const GAS void*)g, (LAS void*)l, 16, 0, 0);
}

// ---------- f32 -> bf16 convert ----------
__global__ void k_cvt_bf16(const float* __restrict__ in, bf16_t* __restrict__ out, int n) {
  int i = (blockIdx.x * blockDim.x + threadIdx.x) * 4;
  if (i + 3 < n) {
    float4 v = *(const float4*)(in + i);
    out[i + 0] = (bf16_t)v.x;
    out[i + 1] = (bf16_t)v.y;
    out[i + 2] = (bf16_t)v.z;
    out[i + 3] = (bf16_t)v.w;
  }
}

// ---------- transpose [Kd,Nd] f32 -> [Nd,Kd] bf16 ----------
__global__ void k_transpose_cvt(const float* __restrict__ in, bf16_t* __restrict__ out,
                                int Kd, int Nd) {
  __shared__ float t[32][33];
  int n0 = blockIdx.x * 32, k0 = blockIdx.y * 32;
  int tx = threadIdx.x, ty = threadIdx.y;
#pragma unroll
  for (int i = 0; i < 32; i += 8)
    t[ty + i][tx] = in[(size_t)(k0 + ty + i) * Nd + n0 + tx];
  __syncthreads();
#pragma unroll
  for (int i = 0; i < 32; i += 8)
    out[(size_t)(n0 + ty + i) * Kd + k0 + tx] = (bf16_t)t[tx][ty + i];
}

// ---------- bf16 MFMA GEMM: C[M,N] = A[M,K] * B^T (B is [N,K]) ----------
__global__ __launch_bounds__(256, 2)
void k_gemm_bt(const bf16_t* __restrict__ A, const bf16_t* __restrict__ B,
               float* __restrict__ C, int M, int N, int K) {
  __shared__ __align__(16) bf16_t As[128 * 32];
  __shared__ __align__(16) bf16_t Bs[128 * 32];
  int tid = threadIdx.x;
  int wave = tid >> 6, lane = tid & 63;
  int wm = wave >> 1, wn = wave & 1;
  int by = blockIdx.y, bx = blockIdx.x;
  const bf16_t* Abase = A + (size_t)by * 128 * K;
  const bf16_t* Bbase = B + (size_t)bx * 128 * K;
  int kc = tid & 3;

  f32x4 acc[4][4];
#pragma unroll
  for (int i = 0; i < 4; ++i)
#pragma unroll
    for (int j = 0; j < 4; ++j) acc[i][j] = (f32x4){0.f, 0.f, 0.f, 0.f};

  for (int k0 = 0; k0 < K; k0 += 32) {
#pragma unroll
    for (int r = 0; r < 2; ++r) {
      int rowe = r * 64 + (tid >> 2);
      const bf16_t* ga = Abase + (size_t)rowe * K + k0 + kc * 8;
      const bf16_t* gb = Bbase + (size_t)rowe * K + k0 + kc * 8;
      gload_lds16(ga, As + (size_t)(r * 256 + wave * 64) * 8);
      gload_lds16(gb, Bs + (size_t)(r * 256 + wave * 64) * 8);
    }
    __syncthreads();
    int kg = lane >> 4, lr = lane & 15;
    bf16x8 af[4], bfv[4];
#pragma unroll
    for (int i = 0; i < 4; ++i) {
      af[i]  = *(const bf16x8*)(As + ((wm * 64 + i * 16 + lr) * 32 + kg * 8));
      bfv[i] = *(const bf16x8*)(Bs + ((wn * 64 + i * 16 + lr) * 32 + kg * 8));
    }
#pragma unroll
    for (int i = 0; i < 4; ++i)
#pragma unroll
      for (int j = 0; j < 4; ++j)
        acc[i][j] = __builtin_amdgcn_mfma_f32_16x16x32_bf16(af[i], bfv[j], acc[i][j], 0, 0, 0);
    __syncthreads();
  }

#pragma unroll
  for (int i = 0; i < 4; ++i) {
    int r0 = by * 128 + wm * 64 + i * 16 + ((lane >> 4) << 2);
#pragma unroll
    for (int j = 0; j < 4; ++j) {
      int c = bx * 128 + wn * 64 + j * 16 + (lane & 15);
      float* Cp = C + (size_t)r0 * N + c;
#pragma unroll
      for (int q = 0; q < 4; ++q) Cp[(size_t)q * N] = acc[i][j][q];
    }
  }
}

// ---------- beta / g ----------
__global__ __launch_bounds__(64)
void k_ab(const float* __restrict__ hidden, const float* __restrict__ Wa,
          const float* __restrict__ Wb, const float* __restrict__ A_log,
          const float* __restrict__ dt_bias, float* __restrict__ g_out,
          float* __restrict__ beta_out) {
  int row = blockIdx.x;
  int lane = threadIdx.x;
  float accA[6] = {0, 0, 0, 0, 0, 0};
  float accB[6] = {0, 0, 0, 0, 0, 0};
  const float* h = hidden + (size_t)row * CC;
  for (int c = lane; c < CC; c += 64) {
    float x = h[c];
    const float* wa = Wa + c * 6;
    const float* wb = Wb + c * 6;
#pragma unroll
    for (int j = 0; j < 6; ++j) {
      accA[j] += x * wa[j];
      accB[j] += x * wb[j];
    }
  }
#pragma unroll
  for (int j = 0; j < 6; ++j) {
    for (int off = 32; off; off >>= 1) {
      accA[j] += __shfl_down(accA[j], off);
      accB[j] += __shfl_down(accB[j], off);
    }
  }
  if (lane == 0) {
#pragma unroll
    for (int j = 0; j < 6; ++j) {
      float a = accA[j] + dt_bias[j];
      float sp = (a > 20.f) ? a : log1pf(expf(a));
      g_out[(size_t)row * 6 + j] = -expf(A_log[j]) * sp;
      beta_out[(size_t)row * 6 + j] = 1.f / (1.f + expf(-accB[j]));
    }
  }
}

// ---------- depthwise causal conv(4) + SiLU (+ optional L2 norm); optional f32/bf16 outs ----------
__global__ void k_conv_silu(const float* __restrict__ pre, int ldpre, int col0,
                            const float* __restrict__ w, float* __restrict__ out,
                            bf16_t* __restrict__ out16, int ld_out, int do_norm) {
  int row = blockIdx.x;     // b*T + t
  int t = row & (TT - 1);
  int h = blockIdx.y;
  int kk = threadIdx.x;
  int perH = blockDim.x;
  int ch = h * perH + kk;
  const float* wp = w + ch * 4;
  float y = 0.f;
#pragma unroll
  for (int i = 0; i < 4; ++i) {
    int tt = t - 3 + i;
    if (tt >= 0) y += wp[i] * pre[(size_t)(row - 3 + i) * ldpre + col0 + ch];
  }
  float s = y / (1.f + expf(-y));
  if (do_norm) {
    float ss = s * s;
#pragma unroll
    for (int off = 32; off; off >>= 1) ss += __shfl_down(ss, off);
    __shared__ float red[2];
    if ((threadIdx.x & 63) == 0) red[threadIdx.x >> 6] = ss;
    __syncthreads();
    float nrm = sqrtf(red[0] + red[1]);
    s = s / (nrm + 1e-6f);
  }
  if (out) out[(size_t)row * ld_out + ch] = s;
  if (out16) out16[(size_t)row * ld_out + ch] = (bf16_t)s;
}

// ============ chunked gated delta rule ============
// Pass 1: M via MFMA (bf16, swizzled); substitution columns in VGPRs with bf16 M reads.
// grid (NC, 12, 2): z=0 solves 256 v-columns (Dv in-place over vn);
//                   z=1 solves 128 k-columns (-W -> Wn16) + produces khatT16.
__global__ __launch_bounds__(256, 2)
void k_chunk1(const bf16_t* __restrict__ kb16, float* dv,
              const float* __restrict__ gdec, const float* __restrict__ beta,
              bf16_t* __restrict__ Wn16, bf16_t* __restrict__ khatT16,
              float* __restrict__ bcum) {
  __shared__ __align__(16) bf16_t ksh[64 * 128];   // [t][k], XOR-swizzled (16B slots)
  __shared__ __align__(16) bf16_t Ms16[64 * 64];   // [t][s] bf16, XOR-swizzled; 0 at/above diag
  __shared__ float bc[64], bet[64];

  int tid = threadIdx.x;
  int bh = blockIdx.y, c = blockIdx.x, z = blockIdx.z;
  int b = bh / HH, h = bh % HH;
  int r0 = b * TT + c * CL;
  size_t cb = (size_t)bh * NC + c;
  int wq = tid >> 6, l = tid & 63;
  int lr = l & 15, lg = l >> 4;

  // stage k chunk (1024 16B slots / 256 thr = 4 iters), pre-XOR'd source -> swizzled LDS
#pragma unroll
  for (int it = 0; it < 4; ++it) {
    int idx = it * 256 + tid;
    int t = idx >> 4, p = idx & 15;
    int kslot = p ^ (t & 7);
    gload_lds16(kb16 + (size_t)(r0 + t) * KD + h * KK + kslot * 8,
                ksh + (size_t)(it * 256 + wq * 64) * 8);
  }
  // g cumsum + beta on wave 0
  if (tid < 64) {
    float val = gdec[(size_t)(r0 + tid) * HH + h];
    bet[tid] = beta[(size_t)(r0 + tid) * HH + h];
#pragma unroll
    for (int off = 1; off < 64; off <<= 1) {
      float o = __shfl_up(val, off, 64);
      if (tid >= off) val += o;
    }
    bc[tid] = val;
    if (z == 0) bcum[cb * CL + tid] = val;
  }
  __syncthreads();
  float bL = bc[63];

  // M = mask(K K^T) * beta_t e^{b_t-b_s} via MFMA; wave wq owns t rows wq*16..+15
  {
    f32x4 pacc[4];
#pragma unroll
    for (int sf = 0; sf < 4; ++sf) pacc[sf] = (f32x4){0.f, 0.f, 0.f, 0.f};
#pragma unroll
    for (int ks_ = 0; ks_ < 4; ++ks_) {
      int trow = wq * 16 + lr;
      bf16x8 aK = *(const bf16x8*)((const char*)ksh + trow * 256 + (((ks_ * 4 + lg) * 16) ^ ((trow & 7) << 4)));
#pragma unroll
      for (int sf = 0; sf < 4; ++sf) {
        int srow = sf * 16 + lr;
        bf16x8 bK = *(const bf16x8*)((const char*)ksh + srow * 256 + (((ks_ * 4 + lg) * 16) ^ ((srow & 7) << 4)));
        pacc[sf] = __builtin_amdgcn_mfma_f32_16x16x32_bf16(aK, bK, pacc[sf], 0, 0, 0);
      }
    }
#pragma unroll
    for (int sf = 0; sf < 4; ++sf)
#pragma unroll
      for (int q = 0; q < 4; ++q) {
        int t = wq * 16 + lg * 4 + q;
        int s = sf * 16 + lr;
        float val = (s < t) ? bet[t] * __expf(bc[t] - bc[s]) * pacc[sf][q] : 0.f;
        *(bf16_t*)((char*)Ms16 + t * 128 + ((s * 2) ^ ((t & 7) << 4))) = (bf16_t)val;
      }
  }

  // RHS
  float rcol[64];
  if (z == 0) {
    const float* dvc = dv + (size_t)r0 * VD + h * VV + tid;
#pragma unroll
    for (int t = 0; t < 64; ++t) rcol[t] = bet[t] * dvc[(size_t)t * VD];
  } else if (tid < 128) {
    int kk = tid;
    bf16_t* kout = khatT16 + cb * (size_t)(KK * CL) + (size_t)kk * CL;
#pragma unroll
    for (int t8 = 0; t8 < 8; ++t8) {
      union { bf16x8 v; bf16_t e[8]; } u;
#pragma unroll
      for (int e = 0; e < 8; ++e) {
        int t = t8 * 8 + e;
        float kval = (float)*(const bf16_t*)((const char*)ksh + t * 256 +
                        ((((kk >> 3) ^ (t & 7)) * 16) + (kk & 7) * 2));
        u.e[e] = (bf16_t)(__expf(bL - bc[t]) * kval);
        rcol[t] = bet[t] * __expf(bc[t]) * kval;
      }
      *(bf16x8*)(kout + t8 * 8) = u.v;
    }
  }
  __syncthreads();
  if (z == 1 && tid >= 128) return;   // no barriers after this point

  // forward substitution, column in registers; bf16 M rows (broadcast b128 reads)
#pragma unroll
  for (int t = 1; t < 64; ++t) {
    float a0 = 0.f, a1 = 0.f, a2 = 0.f, a3 = 0.f;
    const int n8 = (t + 7) >> 3;
#pragma unroll
    for (int s8 = 0; s8 < n8; ++s8) {
      union { bf16x8 v; bf16_t e[8]; } m;
      m.v = *(const bf16x8*)((const char*)Ms16 + t * 128 + ((s8 * 16) ^ ((t & 7) << 4)));
      a0 += (float)m.e[0] * rcol[s8 * 8 + 0];
      a1 += (float)m.e[1] * rcol[s8 * 8 + 1];
      a2 += (float)m.e[2] * rcol[s8 * 8 + 2];
      a3 += (float)m.e[3] * rcol[s8 * 8 + 3];
      a0 += (float)m.e[4] * rcol[s8 * 8 + 4];
      a1 += (float)m.e[5] * rcol[s8 * 8 + 5];
      a2 += (float)m.e[6] * rcol[s8 * 8 + 6];
      a3 += (float)m.e[7] * rcol[s8 * 8 + 7];
    }
    rcol[t] -= (a0 + a1) + (a2 + a3);
  }

  // write out
  if (z == 0) {
    float* dvc = dv + (size_t)r0 * VD + h * VV + tid;
#pragma unroll
    for (int t = 0; t < 64; ++t) dvc[(size_t)t * VD] = rcol[t];
  } else {
    int kk = tid;
#pragma unroll
    for (int t = 0; t < 64; ++t)
      Wn16[(cb * CL + t) * KK + kk] = (bf16_t)(-rcol[t]);
  }
}

// Pass 2: MFMA state propagation. Grid (8 vtiles of 32, 12 bh), 256 thr (4 waves).
// S (f32) lives in accumulators across all 16 chunks (k-split across waves).
// Emits chunk-start states S0^T (bf16 [v][k]) and Zt (bf16 [v][t]).
__global__ __launch_bounds__(256, 1)
void k_chunk2(const float* __restrict__ dv, const bf16_t* __restrict__ Wn16,
              const bf16_t* __restrict__ khatT16, const float* __restrict__ bcum,
              bf16_t* __restrict__ states, bf16_t* __restrict__ Zt) {
  __shared__ __align__(16) bf16_t St[32 * 128];   // [v][k], XOR-swizzled
  __shared__ __align__(16) bf16_t Zl[32 * 64];    // [v][t], XOR-swizzled
  int tid = threadIdx.x;
  int vt = blockIdx.x, bh = blockIdx.y;
  int b = bh / HH, h = bh % HH;
  int wq = tid >> 6, l = tid & 63;
  int lr = l & 15, lg = l >> 4;

  f32x4 acc[2][2];
#pragma unroll
  for (int kf = 0; kf < 2; ++kf)
#pragma unroll
    for (int vf = 0; vf < 2; ++vf) acc[kf][vf] = (f32x4){0.f, 0.f, 0.f, 0.f};

  for (int c = 0; c < NC; ++c) {
    size_t cb = (size_t)bh * NC + c;
    int r0 = b * TT + c * CL;
    float ebL = __expf(bcum[cb * CL + 63]);

    // A: S acc -> St bf16 (swizzled)
#pragma unroll
    for (int kf = 0; kf < 2; ++kf)
#pragma unroll
      for (int vf = 0; vf < 2; ++vf)
#pragma unroll
        for (int q = 0; q < 4; ++q) {
          int k = wq * 32 + kf * 16 + lg * 4 + q;
          int v = vf * 16 + lr;
          *(bf16_t*)((char*)St + v * 256 + ((k * 2) ^ ((v & 7) << 4))) = (bf16_t)acc[kf][vf][q];
        }
    __syncthreads();

    // B: states copy (S0^T for pass 3)
#pragma unroll
    for (int it = 0; it < 2; ++it) {
      int idx = tid + it * 256;
      int v = idx >> 4, slot = idx & 15;
      bf16x8 val = *(const bf16x8*)((const char*)St + v * 256 + ((slot * 16) ^ ((v & 7) << 4)));
      *(bf16x8*)(states + ((size_t)cb * 256 + vt * 32 + v) * 128 + slot * 8) = val;
    }

    // Z = Dv + (-W) * S  : per wave 16t x 32v
    f32x4 zacc[2];
#pragma unroll
    for (int vf = 0; vf < 2; ++vf)
#pragma unroll
      for (int q = 0; q < 4; ++q) {
        int t = wq * 16 + lg * 4 + q;
        zacc[vf][q] = dv[(size_t)(r0 + t) * VD + h * VV + vt * 32 + vf * 16 + lr];
      }
#pragma unroll
    for (int ks_ = 0; ks_ < 4; ++ks_) {
      bf16x8 aW = *(const bf16x8*)(Wn16 + (cb * CL + wq * 16 + lr) * KK + ks_ * 32 + lg * 8);
#pragma unroll
      for (int vf = 0; vf < 2; ++vf) {
        int v = vf * 16 + lr;
        bf16x8 bS = *(const bf16x8*)((const char*)St + v * 256 + (((ks_ * 32 + lg * 8) * 2) ^ ((v & 7) << 4)));
        zacc[vf] = __builtin_amdgcn_mfma_f32_16x16x32_bf16(aW, bS, zacc[vf], 0, 0, 0);
      }
    }
    // Zl write (bf16 [v][t] swizzled)
#pragma unroll
    for (int vf = 0; vf < 2; ++vf)
#pragma unroll
      for (int q = 0; q < 4; ++q) {
        int t = wq * 16 + lg * 4 + q;
        int v = vf * 16 + lr;
        *(bf16_t*)((char*)Zl + v * 128 + ((t * 2) ^ ((v & 7) << 4))) = (bf16_t)zacc[vf][q];
      }
    __syncthreads();

    // D: Zt copy to global
    {
      int v = tid >> 3, slot = tid & 7;
      bf16x8 val = *(const bf16x8*)((const char*)Zl + v * 128 + ((slot * 16) ^ ((v & 7) << 4)));
      *(bf16x8*)(Zt + ((size_t)cb * 256 + vt * 32 + v) * 64 + slot * 8) = val;
    }
    // S decay + S += khatT * Z
#pragma unroll
    for (int kf = 0; kf < 2; ++kf)
#pragma unroll
      for (int vf = 0; vf < 2; ++vf)
#pragma unroll
        for (int q = 0; q < 4; ++q) acc[kf][vf][q] *= ebL;
#pragma unroll
    for (int ts = 0; ts < 2; ++ts) {
      bf16x8 aK[2], bZ[2];
#pragma unroll
      for (int kf = 0; kf < 2; ++kf)
        aK[kf] = *(const bf16x8*)(khatT16 + (cb * KK + wq * 32 + kf * 16 + lr) * CL + ts * 32 + lg * 8);
#pragma unroll
      for (int vf = 0; vf < 2; ++vf) {
        int v = vf * 16 + lr;
        bZ[vf] = *(const bf16x8*)((const char*)Zl + v * 128 + (((ts * 32 + lg * 8) * 2) ^ ((v & 7) << 4)));
      }
#pragma unroll
      for (int kf = 0; kf < 2; ++kf)
#pragma unroll
        for (int vf = 0; vf < 2; ++vf)
          acc[kf][vf] = __builtin_amdgcn_mfma_f32_16x16x32_bf16(aK[kf], bZ[vf], acc[kf][vf], 0, 0, 0);
    }
  }
}

// Pass 3: o = e^{b_t} q^T S0 + P Z (MFMA) + fused gated RMSNorm -> ovd bf16.
__global__ __launch_bounds__(256, 1)
void k_chunk3(const bf16_t* __restrict__ qb16, const bf16_t* __restrict__ kb16,
              const bf16_t* __restrict__ Zt, const bf16_t* __restrict__ states,
              const float* __restrict__ bcum, const float* __restrict__ fgate,
              const float* __restrict__ onorm_w, bf16_t* __restrict__ ovd) {
  __shared__ __align__(16) bf16_t qs[64 * 128];   // [t][k] swizzled via pre-XOR source
  __shared__ __align__(16) bf16_t ksh[64 * 128];
  __shared__ __align__(16) bf16_t Pl[64 * 64];    // [t][s] swizzled
  __shared__ float bcs[64];
  __shared__ float sred[4][64];

  int tid = threadIdx.x;
  int c = blockIdx.x, bh = blockIdx.y;
  int b = bh / HH, h = bh % HH;
  int r0 = b * TT + c * CL;
  size_t cb = (size_t)bh * NC + c;
  int wq = tid >> 6, l = tid & 63;
  int lr = l & 15, lg = l >> 4;

  if (tid < 64) bcs[tid] = bcum[cb * CL + tid];
#pragma unroll
  for (int it = 0; it < 4; ++it) {
    int idx = it * 256 + tid;
    int t = idx >> 4, p = idx & 15;
    int kslot = p ^ (t & 7);
    gload_lds16(qb16 + (size_t)(r0 + t) * KD + h * KK + kslot * 8,
                qs + (size_t)(it * 256 + wq * 64) * 8);
    gload_lds16(kb16 + (size_t)(r0 + t) * KD + h * KK + kslot * 8,
                ksh + (size_t)(it * 256 + wq * 64) * 8);
  }
  __syncthreads();

  // P = mask(q k^T) * e^{b_t-b_s}; wave wq covers t rows wq*16..+15
  f32x4 pacc[4];
#pragma unroll
  for (int sf = 0; sf < 4; ++sf) pacc[sf] = (f32x4){0.f, 0.f, 0.f, 0.f};
#pragma unroll
  for (int ks_ = 0; ks_ < 4; ++ks_) {
    int trow = wq * 16 + lr;
    bf16x8 aQ = *(const bf16x8*)((const char*)qs + trow * 256 + (((ks_ * 4 + lg) * 16) ^ ((trow & 7) << 4)));
#pragma unroll
    for (int sf = 0; sf < 4; ++sf) {
      int srow = sf * 16 + lr;
      bf16x8 bK = *(const bf16x8*)((const char*)ksh + srow * 256 + (((ks_ * 4 + lg) * 16) ^ ((srow & 7) << 4)));
      pacc[sf] = __builtin_amdgcn_mfma_f32_16x16x32_bf16(aQ, bK, pacc[sf], 0, 0, 0);
    }
  }
#pragma unroll
  for (int sf = 0; sf < 4; ++sf)
#pragma unroll
    for (int q = 0; q < 4; ++q) {
      int t = wq * 16 + lg * 4 + q;
      int s = sf * 16 + lr;
      float val = (s <= t) ? pacc[sf][q] * __expf(bcs[t] - bcs[s]) : 0.f;
      *(bf16_t*)((char*)Pl + t * 128 + ((s * 2) ^ ((t & 7) << 4))) = (bf16_t)val;
    }
  __syncthreads();

  // O: wave wq covers v cols wq*64..+63; oacc = qhat*S0^T + P*Zt
  f32x4 oacc[4][4];
#pragma unroll
  for (int ti = 0; ti < 4; ++ti)
#pragma unroll
    for (int vj = 0; vj < 4; ++vj) oacc[ti][vj] = (f32x4){0.f, 0.f, 0.f, 0.f};

#pragma unroll
  for (int ks_ = 0; ks_ < 4; ++ks_) {
    bf16x8 aQ[4];
#pragma unroll
    for (int ti = 0; ti < 4; ++ti) {
      int t = ti * 16 + lr;
      union { bf16x8 v; bf16_t e[8]; } u;
      u.v = *(const bf16x8*)((const char*)qs + t * 256 + (((ks_ * 4 + lg) * 16) ^ ((t & 7) << 4)));
      float eb = __expf(bcs[t]);
#pragma unroll
      for (int e = 0; e < 8; ++e) u.e[e] = (bf16_t)((float)u.e[e] * eb);
      aQ[ti] = u.v;
    }
#pragma unroll
    for (int vj = 0; vj < 4; ++vj) {
      int vrow = wq * 64 + vj * 16 + lr;
      bf16x8 bS = *(const bf16x8*)(states + ((size_t)cb * 256 + vrow) * 128 + ks_ * 32 + lg * 8);
#pragma unroll
      for (int ti = 0; ti < 4; ++ti)
        oacc[ti][vj] = __builtin_amdgcn_mfma_f32_16x16x32_bf16(aQ[ti], bS, oacc[ti][vj], 0, 0, 0);
    }
  }
#pragma unroll
  for (int ts = 0; ts < 2; ++ts) {
    bf16x8 aP[4];
#pragma unroll
    for (int ti = 0; ti < 4; ++ti) {
      int t = ti * 16 + lr;
      aP[ti] = *(const bf16x8*)((const char*)Pl + t * 128 + (((ts * 4 + lg) * 16) ^ ((t & 7) << 4)));
    }
#pragma unroll
    for (int vj = 0; vj < 4; ++vj) {
      int vrow = wq * 64 + vj * 16 + lr;
      bf16x8 bZ = *(const bf16x8*)(Zt + ((size_t)cb * 256 + vrow) * 64 + ts * 32 + lg * 8);
#pragma unroll
      for (int ti = 0; ti < 4; ++ti)
        oacc[ti][vj] = __builtin_amdgcn_mfma_f32_16x16x32_bf16(aP[ti], bZ, oacc[ti][vj], 0, 0, 0);
    }
  }

  // ---- fused gated RMSNorm ----
  // per-lane partials: sum over this lane's 4 v-positions for each of its 16 t's
  float sum2[4][4];
#pragma unroll
  for (int ti = 0; ti < 4; ++ti)
#pragma unroll
    for (int q = 0; q < 4; ++q) {
      float s = 0.f;
#pragma unroll
      for (int vj = 0; vj < 4; ++vj) s += oacc[ti][vj][q] * oacc[ti][vj][q];
      sum2[ti][q] = s;
    }
  // reduce across the 16-lane lr group (same t-set)
#pragma unroll
  for (int mk = 1; mk < 16; mk <<= 1)
#pragma unroll
    for (int ti = 0; ti < 4; ++ti)
#pragma unroll
      for (int q = 0; q < 4; ++q)
        sum2[ti][q] += __shfl_xor(sum2[ti][q], mk, 64);
  if (lr == 0) {
#pragma unroll
    for (int ti = 0; ti < 4; ++ti)
#pragma unroll
      for (int q = 0; q < 4; ++q)
        sred[wq][ti * 16 + lg * 4 + q] = sum2[ti][q];
  }
  __syncthreads();

  float onv[4];
#pragma unroll
  for (int vj = 0; vj < 4; ++vj) onv[vj] = onorm_w[wq * 64 + vj * 16 + lr];
#pragma unroll
  for (int ti = 0; ti < 4; ++ti)
#pragma unroll
    for (int q = 0; q < 4; ++q) {
      int t = ti * 16 + lg * 4 + q;
      float tot = sred[0][t] + sred[1][t] + sred[2][t] + sred[3][t];
      float rn = rsqrtf(tot * (1.f / VV) + 1e-5f);
#pragma unroll
      for (int vj = 0; vj < 4; ++vj) {
        int v = wq * 64 + vj * 16 + lr;
        float gate = fgate[(size_t)(r0 + t) * VD + h * VV + v];
        float y = oacc[ti][vj][q] * rn * onv[vj] * (gate / (1.f + expf(-gate)));
        ovd[(size_t)(r0 + t) * VD + h * VV + v] = (bf16_t)y;
      }
    }
}

extern "C" void kernel_launch(void* const* d_in, const int* in_sizes, int n_in,
                              void* d_out, int out_size, void* d_ws, size_t ws_size,
                              hipStream_t stream) {
  const float* hidden = (const float*)d_in[0];
  const float* Wq = (const float*)d_in[1];
  const float* Wk = (const float*)d_in[2];
  const float* Wv = (const float*)d_in[3];
  const float* Wa = (const float*)d_in[4];
  const float* Wb = (const float*)d_in[5];
  const float* A_log = (const float*)d_in[6];
  const float* dt_bias = (const float*)d_in[7];
  const float* qconv = (const float*)d_in[8];
  const float* kconv = (const float*)d_in[9];
  const float* vconv = (const float*)d_in[10];
  const float* Wg = (const float*)d_in[11];
  const float* onorm = (const float*)d_in[12];
  const float* Wo = (const float*)d_in[13];
  float* out = (float*)d_out;

  char* ws = (char*)d_ws;
  size_t off = 0;
  auto alloc = [&](size_t bytes) {
    void* p = ws + off;
    off += (bytes + 255) & ~(size_t)255;
    return p;
  };
  const int M = BB * TT;  // 2048
  bf16_t* hbf   = (bf16_t*)alloc((size_t)M * CC * 2);       // aliased by Wn16/khatT16 later
  bf16_t* WcatT = (bf16_t*)alloc((size_t)NCAT * CC * 2);
  bf16_t* WoT   = (bf16_t*)alloc((size_t)CC * VD * 2);
  float*  fqkv  = (float*) alloc((size_t)M * NQKV * 4);     // aliased by states later
  float*  fgate = (float*) alloc((size_t)M * VD * 4);
  float*  kn    = (float*) alloc((size_t)M * KD * 4);       // aliased by Zt later
  float*  vn    = (float*) alloc((size_t)M * VD * 4);       // becomes Dv in pass 1
  float*  gdec  = (float*) alloc((size_t)M * HH * 4);
  float*  beta  = (float*) alloc((size_t)M * HH * 4);
  bf16_t* ovd   = (bf16_t*)alloc((size_t)M * VD * 2);
  bf16_t* qb16  = (bf16_t*)alloc((size_t)M * KD * 2);
  bf16_t* kb16  = (bf16_t*)alloc((size_t)M * KD * 2);
  float*  bcum  = (float*) alloc((size_t)12 * NC * CL * 4);

  // aliases (stream-ordered lifetime separation):
  bf16_t* Wn16    = (bf16_t*)hbf;                     // 12*16*64*128 bf16 = 3.15MB
  bf16_t* khatT16 = Wn16 + (size_t)12 * NC * CL * KK; // +3.15MB (hbf is 8.4MB)
  bf16_t* states  = (bf16_t*)fqkv;                    // 12*16*256*128 bf16 = 12.6MB
  bf16_t* Zt      = (bf16_t*)kn;                      // 12*16*256*64 bf16 = 6.3MB

  // pre-pass
  k_cvt_bf16<<<(M * CC / 4 + 255) / 256, 256, 0, stream>>>(hidden, hbf, M * CC);
  k_transpose_cvt<<<dim3(KD / 32, CC / 32), dim3(32, 8), 0, stream>>>(Wq, WcatT, CC, KD);
  k_transpose_cvt<<<dim3(KD / 32, CC / 32), dim3(32, 8), 0, stream>>>(Wk, WcatT + (size_t)768 * CC, CC, KD);
  k_transpose_cvt<<<dim3(VD / 32, CC / 32), dim3(32, 8), 0, stream>>>(Wv, WcatT + (size_t)1536 * CC, CC, VD);
  k_transpose_cvt<<<dim3(VD / 32, CC / 32), dim3(32, 8), 0, stream>>>(Wg, WcatT + (size_t)3072 * CC, CC, VD);
  k_transpose_cvt<<<dim3(CC / 32, VD / 32), dim3(32, 8), 0, stream>>>(Wo, WoT, VD, CC);

  // projections
  k_gemm_bt<<<dim3(NQKV / 128, M / 128), 256, 0, stream>>>(hbf, WcatT, fqkv, M, NQKV, CC);
  k_gemm_bt<<<dim3(VD / 128, M / 128), 256, 0, stream>>>(hbf, WcatT + (size_t)3072 * CC, fgate, M, VD, CC);

  // beta / g
  k_ab<<<M, 64, 0, stream>>>(hidden, Wa, Wb, A_log, dt_bias, gdec, beta);

  // conv + silu (+norm for q,k)
  k_conv_silu<<<dim3(M, HH), 128, 0, stream>>>(fqkv, NQKV, 0, qconv, nullptr, qb16, KD, 1);
  k_conv_silu<<<dim3(M, HH), 128, 0, stream>>>(fqkv, NQKV, 768, kconv, nullptr, kb16, KD, 1);
  k_conv_silu<<<dim3(M, HH), 256, 0, stream>>>(fqkv, NQKV, 1536, vconv, vn, nullptr, VD, 0);

  // chunked gated delta rule (hbf dead -> Wn16/khatT16; fqkv dead -> states; kn dead -> Zt)
  k_chunk1<<<dim3(NC, 12, 2), 256, 0, stream>>>(kb16, vn, gdec, beta, Wn16, khatT16, bcum);
  k_chunk2<<<dim3(8, 12), 256, 0, stream>>>(vn, Wn16, khatT16, bcum, states, Zt);
  k_chunk3<<<dim3(NC, 12), 256, 0, stream>>>(qb16, kb16, Zt, states, bcum, fgate, onorm, ovd);

  // output projection
  k_gemm_bt<<<dim3(CC / 128, M / 128), 256, 0, stream>>>(ovd, WoT, out, M, CC, VD);
}

// Round 6
// 281.438 us; speedup vs baseline: 1.1341x; 1.1341x over previous
//
#include <hip/hip_runtime.h>
#include <hip/hip_bf16.h>
#include <math.h>

typedef __bf16 bf16_t;
typedef __attribute__((ext_vector_type(8))) __bf16 bf16x8;
typedef __attribute__((ext_vector_type(4))) float f32x4;

#define GAS __attribute__((address_space(1)))
#define LAS __attribute__((address_space(3)))

#define BB 2
#define TT 1024
#define CC 2048
#define HH 6
#define KK 128
#define VV 256
#define KD 768
#define VD 1536
#define NQKV 3072
#define NCAT 4608
#define NC 16     // chunks per sequence
#define CL 64     // chunk length

__device__ __forceinline__ void gload_lds16(const void* g, void* l) {
  __builtin_amdgcn_global_load_lds((const GAS void*)g, (LAS void*)l, 16, 0, 0);
}

// ---------- f32 -> bf16 convert ----------
__global__ void k_cvt_bf16(const float* __restrict__ in, bf16_t* __restrict__ out, int n) {
  int i = (blockIdx.x * blockDim.x + threadIdx.x) * 4;
  if (i + 3 < n) {
    float4 v = *(const float4*)(in + i);
    out[i + 0] = (bf16_t)v.x;
    out[i + 1] = (bf16_t)v.y;
    out[i + 2] = (bf16_t)v.z;
    out[i + 3] = (bf16_t)v.w;
  }
}

// ---------- transpose [Kd,Nd] f32 -> [Nd,Kd] bf16 ----------
__global__ void k_transpose_cvt(const float* __restrict__ in, bf16_t* __restrict__ out,
                                int Kd, int Nd) {
  __shared__ float t[32][33];
  int n0 = blockIdx.x * 32, k0 = blockIdx.y * 32;
  int tx = threadIdx.x, ty = threadIdx.y;
#pragma unroll
  for (int i = 0; i < 32; i += 8)
    t[ty + i][tx] = in[(size_t)(k0 + ty + i) * Nd + n0 + tx];
  __syncthreads();
#pragma unroll
  for (int i = 0; i < 32; i += 8)
    out[(size_t)(n0 + ty + i) * Kd + k0 + tx] = (bf16_t)t[tx][ty + i];
}

// ---------- bf16 MFMA GEMM: C[M,N] = A[M,K] * B^T (B is [N,K]) ----------
__global__ __launch_bounds__(256, 2)
void k_gemm_bt(const bf16_t* __restrict__ A, const bf16_t* __restrict__ B,
               float* __restrict__ C, int M, int N, int K) {
  __shared__ __align__(16) bf16_t As[128 * 32];
  __shared__ __align__(16) bf16_t Bs[128 * 32];
  int tid = threadIdx.x;
  int wave = tid >> 6, lane = tid & 63;
  int wm = wave >> 1, wn = wave & 1;
  int by = blockIdx.y, bx = blockIdx.x;
  const bf16_t* Abase = A + (size_t)by * 128 * K;
  const bf16_t* Bbase = B + (size_t)bx * 128 * K;
  int kc = tid & 3;

  f32x4 acc[4][4];
#pragma unroll
  for (int i = 0; i < 4; ++i)
#pragma unroll
    for (int j = 0; j < 4; ++j) acc[i][j] = (f32x4){0.f, 0.f, 0.f, 0.f};

  for (int k0 = 0; k0 < K; k0 += 32) {
#pragma unroll
    for (int r = 0; r < 2; ++r) {
      int rowe = r * 64 + (tid >> 2);
      const bf16_t* ga = Abase + (size_t)rowe * K + k0 + kc * 8;
      const bf16_t* gb = Bbase + (size_t)rowe * K + k0 + kc * 8;
      gload_lds16(ga, As + (size_t)(r * 256 + wave * 64) * 8);
      gload_lds16(gb, Bs + (size_t)(r * 256 + wave * 64) * 8);
    }
    __syncthreads();
    int kg = lane >> 4, lr = lane & 15;
    bf16x8 af[4], bfv[4];
#pragma unroll
    for (int i = 0; i < 4; ++i) {
      af[i]  = *(const bf16x8*)(As + ((wm * 64 + i * 16 + lr) * 32 + kg * 8));
      bfv[i] = *(const bf16x8*)(Bs + ((wn * 64 + i * 16 + lr) * 32 + kg * 8));
    }
#pragma unroll
    for (int i = 0; i < 4; ++i)
#pragma unroll
      for (int j = 0; j < 4; ++j)
        acc[i][j] = __builtin_amdgcn_mfma_f32_16x16x32_bf16(af[i], bfv[j], acc[i][j], 0, 0, 0);
    __syncthreads();
  }

#pragma unroll
  for (int i = 0; i < 4; ++i) {
    int r0 = by * 128 + wm * 64 + i * 16 + ((lane >> 4) << 2);
#pragma unroll
    for (int j = 0; j < 4; ++j) {
      int c = bx * 128 + wn * 64 + j * 16 + (lane & 15);
      float* Cp = C + (size_t)r0 * N + c;
#pragma unroll
      for (int q = 0; q < 4; ++q) Cp[(size_t)q * N] = acc[i][j][q];
    }
  }
}

// ---------- beta / g ----------
__global__ __launch_bounds__(64)
void k_ab(const float* __restrict__ hidden, const float* __restrict__ Wa,
          const float* __restrict__ Wb, const float* __restrict__ A_log,
          const float* __restrict__ dt_bias, float* __restrict__ g_out,
          float* __restrict__ beta_out) {
  int row = blockIdx.x;
  int lane = threadIdx.x;
  float accA[6] = {0, 0, 0, 0, 0, 0};
  float accB[6] = {0, 0, 0, 0, 0, 0};
  const float* h = hidden + (size_t)row * CC;
  for (int c = lane; c < CC; c += 64) {
    float x = h[c];
    const float* wa = Wa + c * 6;
    const float* wb = Wb + c * 6;
#pragma unroll
    for (int j = 0; j < 6; ++j) {
      accA[j] += x * wa[j];
      accB[j] += x * wb[j];
    }
  }
#pragma unroll
  for (int j = 0; j < 6; ++j) {
    for (int off = 32; off; off >>= 1) {
      accA[j] += __shfl_down(accA[j], off);
      accB[j] += __shfl_down(accB[j], off);
    }
  }
  if (lane == 0) {
#pragma unroll
    for (int j = 0; j < 6; ++j) {
      float a = accA[j] + dt_bias[j];
      float sp = (a > 20.f) ? a : log1pf(expf(a));
      g_out[(size_t)row * 6 + j] = -expf(A_log[j]) * sp;
      beta_out[(size_t)row * 6 + j] = 1.f / (1.f + expf(-accB[j]));
    }
  }
}

// ---------- depthwise causal conv(4) + SiLU (+ optional L2 norm); optional f32/bf16 outs ----------
__global__ void k_conv_silu(const float* __restrict__ pre, int ldpre, int col0,
                            const float* __restrict__ w, float* __restrict__ out,
                            bf16_t* __restrict__ out16, int ld_out, int do_norm) {
  int row = blockIdx.x;     // b*T + t
  int t = row & (TT - 1);
  int h = blockIdx.y;
  int kk = threadIdx.x;
  int perH = blockDim.x;
  int ch = h * perH + kk;
  const float* wp = w + ch * 4;
  float y = 0.f;
#pragma unroll
  for (int i = 0; i < 4; ++i) {
    int tt = t - 3 + i;
    if (tt >= 0) y += wp[i] * pre[(size_t)(row - 3 + i) * ldpre + col0 + ch];
  }
  float s = y / (1.f + expf(-y));
  if (do_norm) {
    float ss = s * s;
#pragma unroll
    for (int off = 32; off; off >>= 1) ss += __shfl_down(ss, off);
    __shared__ float red[2];
    if ((threadIdx.x & 63) == 0) red[threadIdx.x >> 6] = ss;
    __syncthreads();
    float nrm = sqrtf(red[0] + red[1]);
    s = s / (nrm + 1e-6f);
  }
  if (out) out[(size_t)row * ld_out + ch] = s;
  if (out16) out16[(size_t)row * ld_out + ch] = (bf16_t)s;
}

// ============ chunked gated delta rule ============
// Pass 1: M via MFMA (f32 LDS); substitution columns in REGISTERS via 4 named
// static blocks (no runtime indexing -> no scratch).
// grid (NC, 12, 2): z=0 solves 256 v-columns (Dv in-place over vn);
//                   z=1 solves 128 k-columns (-W -> Wn16) + produces khatT16.
#define XSET(t, v) { if ((t) < 16) x0[(t)] = (v); else if ((t) < 32) x1[(t)-16] = (v); \
                     else if ((t) < 48) x2[(t)-32] = (v); else x3[(t)-48] = (v); }
#define XGET(t) ((t) < 16 ? x0[(t)] : (t) < 32 ? x1[(t)-16] : (t) < 48 ? x2[(t)-32] : x3[(t)-48])

__global__ __launch_bounds__(256, 2)
void k_chunk1(const bf16_t* __restrict__ kb16, float* dv,
              const float* __restrict__ gdec, const float* __restrict__ beta,
              bf16_t* __restrict__ Wn16, bf16_t* __restrict__ khatT16,
              float* __restrict__ bcum) {
  __shared__ __align__(16) bf16_t ksh[64 * 128];   // [t][k], XOR-swizzled (16B slots)
  __shared__ __align__(16) float Msf[64 * 68];     // [t][s] f32, +4 pad; 0 at/above diag
  __shared__ float bc[64], bet[64];

  int tid = threadIdx.x;
  int bh = blockIdx.y, c = blockIdx.x, z = blockIdx.z;
  int b = bh / HH, h = bh % HH;
  int r0 = b * TT + c * CL;
  size_t cb = (size_t)bh * NC + c;
  int wq = tid >> 6, l = tid & 63;
  int lr = l & 15, lg = l >> 4;

  // stage k chunk (1024 16B slots / 256 thr = 4 iters), pre-XOR'd source -> swizzled LDS
#pragma unroll
  for (int it = 0; it < 4; ++it) {
    int idx = it * 256 + tid;
    int t = idx >> 4, p = idx & 15;
    int kslot = p ^ (t & 7);
    gload_lds16(kb16 + (size_t)(r0 + t) * KD + h * KK + kslot * 8,
                ksh + (size_t)(it * 256 + wq * 64) * 8);
  }
  // g cumsum + beta on wave 0
  if (tid < 64) {
    float val = gdec[(size_t)(r0 + tid) * HH + h];
    bet[tid] = beta[(size_t)(r0 + tid) * HH + h];
#pragma unroll
    for (int off = 1; off < 64; off <<= 1) {
      float o = __shfl_up(val, off, 64);
      if (tid >= off) val += o;
    }
    bc[tid] = val;
    if (z == 0) bcum[cb * CL + tid] = val;
  }
  __syncthreads();
  float bL = bc[63];

  // M = mask(K K^T) * beta_t e^{b_t-b_s} via MFMA -> Msf f32
  {
    f32x4 pacc[4];
#pragma unroll
    for (int sf = 0; sf < 4; ++sf) pacc[sf] = (f32x4){0.f, 0.f, 0.f, 0.f};
#pragma unroll
    for (int ks_ = 0; ks_ < 4; ++ks_) {
      int trow = wq * 16 + lr;
      bf16x8 aK = *(const bf16x8*)((const char*)ksh + trow * 256 + (((ks_ * 4 + lg) * 16) ^ ((trow & 7) << 4)));
#pragma unroll
      for (int sf = 0; sf < 4; ++sf) {
        int srow = sf * 16 + lr;
        bf16x8 bK = *(const bf16x8*)((const char*)ksh + srow * 256 + (((ks_ * 4 + lg) * 16) ^ ((srow & 7) << 4)));
        pacc[sf] = __builtin_amdgcn_mfma_f32_16x16x32_bf16(aK, bK, pacc[sf], 0, 0, 0);
      }
    }
#pragma unroll
    for (int sf = 0; sf < 4; ++sf)
#pragma unroll
      for (int q = 0; q < 4; ++q) {
        int t = wq * 16 + lg * 4 + q;
        int s = sf * 16 + lr;
        Msf[t * 68 + s] = (s < t) ? bet[t] * __expf(bc[t] - bc[s]) * pacc[sf][q] : 0.f;
      }
  }

  // RHS into register blocks (STATIC indexing only)
  float x0[16], x1[16], x2[16], x3[16];
  if (z == 0) {
    const float* dvc = dv + (size_t)r0 * VD + h * VV + tid;
#pragma unroll
    for (int t = 0; t < 64; ++t) XSET(t, bet[t] * dvc[(size_t)t * VD]);
  } else if (tid < 128) {
    int kk = tid;
    bf16_t* kout = khatT16 + cb * (size_t)(KK * CL) + (size_t)kk * CL;
#pragma unroll
    for (int t8 = 0; t8 < 8; ++t8) {
      union { bf16x8 v; bf16_t e[8]; } u;
#pragma unroll
      for (int e = 0; e < 8; ++e) {
        int t = t8 * 8 + e;
        float kval = (float)*(const bf16_t*)((const char*)ksh + t * 256 +
                        ((((kk >> 3) ^ (t & 7)) * 16) + (kk & 7) * 2));
        u.e[e] = (bf16_t)(__expf(bL - bc[t]) * kval);
        XSET(t, bet[t] * __expf(bc[t]) * kval);
      }
      *(bf16x8*)(kout + t8 * 8) = u.v;
    }
  }
  __syncthreads();
  if (z == 1 && tid >= 128) return;   // no barriers after this point

  // ---- forward substitution: 4 static triangles + 6 static off-diag updates ----
#define TRI(x, tb) \
  _Pragma("unroll") for (int tt = 1; tt < 16; ++tt) { \
    float a = 0.f; \
    _Pragma("unroll") for (int ss = 0; ss < tt; ++ss) \
      a += Msf[(tb + tt) * 68 + tb + ss] * x[ss]; \
    x[tt] -= a; \
  }
#define OFFB(xd, xs, tb, sb) \
  _Pragma("unroll") for (int tt = 0; tt < 16; ++tt) { \
    const f32x4* row = (const f32x4*)&Msf[(tb + tt) * 68 + sb]; \
    float a0 = 0.f, a1 = 0.f, a2 = 0.f, a3 = 0.f; \
    _Pragma("unroll") for (int s4 = 0; s4 < 4; ++s4) { \
      f32x4 m = row[s4]; \
      a0 += m[0] * xs[s4 * 4 + 0]; \
      a1 += m[1] * xs[s4 * 4 + 1]; \
      a2 += m[2] * xs[s4 * 4 + 2]; \
      a3 += m[3] * xs[s4 * 4 + 3]; \
    } \
    xd[tt] -= (a0 + a1) + (a2 + a3); \
  }

  TRI(x0, 0)
  OFFB(x1, x0, 16, 0)
  TRI(x1, 16)
  OFFB(x2, x0, 32, 0)
  OFFB(x2, x1, 32, 16)
  TRI(x2, 32)
  OFFB(x3, x0, 48, 0)
  OFFB(x3, x1, 48, 16)
  OFFB(x3, x2, 48, 32)
  TRI(x3, 48)

  // write out
  if (z == 0) {
    float* dvc = dv + (size_t)r0 * VD + h * VV + tid;
#pragma unroll
    for (int t = 0; t < 64; ++t) dvc[(size_t)t * VD] = XGET(t);
  } else {
    int kk = tid;
#pragma unroll
    for (int t = 0; t < 64; ++t)
      Wn16[(cb * CL + t) * KK + kk] = (bf16_t)(-XGET(t));
  }
}

// Pass 2: MFMA state propagation. Grid (8 vtiles of 32, 12 bh), 256 thr (4 waves).
// S (f32) lives in accumulators across all 16 chunks (k-split across waves).
// Emits chunk-start states S0^T (bf16 [v][k]) and Zt (bf16 [v][t]).
__global__ __launch_bounds__(256, 1)
void k_chunk2(const float* __restrict__ dv, const bf16_t* __restrict__ Wn16,
              const bf16_t* __restrict__ khatT16, const float* __restrict__ bcum,
              bf16_t* __restrict__ states, bf16_t* __restrict__ Zt) {
  __shared__ __align__(16) bf16_t St[32 * 128];   // [v][k], XOR-swizzled
  __shared__ __align__(16) bf16_t Zl[32 * 64];    // [v][t], XOR-swizzled
  int tid = threadIdx.x;
  int vt = blockIdx.x, bh = blockIdx.y;
  int b = bh / HH, h = bh % HH;
  int wq = tid >> 6, l = tid & 63;
  int lr = l & 15, lg = l >> 4;

  f32x4 acc[2][2];
#pragma unroll
  for (int kf = 0; kf < 2; ++kf)
#pragma unroll
    for (int vf = 0; vf < 2; ++vf) acc[kf][vf] = (f32x4){0.f, 0.f, 0.f, 0.f};

  for (int c = 0; c < NC; ++c) {
    size_t cb = (size_t)bh * NC + c;
    int r0 = b * TT + c * CL;
    float ebL = __expf(bcum[cb * CL + 63]);

    // A: S acc -> St bf16 (swizzled)
#pragma unroll
    for (int kf = 0; kf < 2; ++kf)
#pragma unroll
      for (int vf = 0; vf < 2; ++vf)
#pragma unroll
        for (int q = 0; q < 4; ++q) {
          int k = wq * 32 + kf * 16 + lg * 4 + q;
          int v = vf * 16 + lr;
          *(bf16_t*)((char*)St + v * 256 + ((k * 2) ^ ((v & 7) << 4))) = (bf16_t)acc[kf][vf][q];
        }
    __syncthreads();

    // B: states copy (S0^T for pass 3)
#pragma unroll
    for (int it = 0; it < 2; ++it) {
      int idx = tid + it * 256;
      int v = idx >> 4, slot = idx & 15;
      bf16x8 val = *(const bf16x8*)((const char*)St + v * 256 + ((slot * 16) ^ ((v & 7) << 4)));
      *(bf16x8*)(states + ((size_t)cb * 256 + vt * 32 + v) * 128 + slot * 8) = val;
    }

    // Z = Dv + (-W) * S  : per wave 16t x 32v
    f32x4 zacc[2];
#pragma unroll
    for (int vf = 0; vf < 2; ++vf)
#pragma unroll
      for (int q = 0; q < 4; ++q) {
        int t = wq * 16 + lg * 4 + q;
        zacc[vf][q] = dv[(size_t)(r0 + t) * VD + h * VV + vt * 32 + vf * 16 + lr];
      }
#pragma unroll
    for (int ks_ = 0; ks_ < 4; ++ks_) {
      bf16x8 aW = *(const bf16x8*)(Wn16 + (cb * CL + wq * 16 + lr) * KK + ks_ * 32 + lg * 8);
#pragma unroll
      for (int vf = 0; vf < 2; ++vf) {
        int v = vf * 16 + lr;
        bf16x8 bS = *(const bf16x8*)((const char*)St + v * 256 + (((ks_ * 32 + lg * 8) * 2) ^ ((v & 7) << 4)));
        zacc[vf] = __builtin_amdgcn_mfma_f32_16x16x32_bf16(aW, bS, zacc[vf], 0, 0, 0);
      }
    }
    // Zl write (bf16 [v][t] swizzled)
#pragma unroll
    for (int vf = 0; vf < 2; ++vf)
#pragma unroll
      for (int q = 0; q < 4; ++q) {
        int t = wq * 16 + lg * 4 + q;
        int v = vf * 16 + lr;
        *(bf16_t*)((char*)Zl + v * 128 + ((t * 2) ^ ((v & 7) << 4))) = (bf16_t)zacc[vf][q];
      }
    __syncthreads();

    // D: Zt copy to global
    {
      int v = tid >> 3, slot = tid & 7;
      bf16x8 val = *(const bf16x8*)((const char*)Zl + v * 128 + ((slot * 16) ^ ((v & 7) << 4)));
      *(bf16x8*)(Zt + ((size_t)cb * 256 + vt * 32 + v) * 64 + slot * 8) = val;
    }
    // S decay + S += khatT * Z
#pragma unroll
    for (int kf = 0; kf < 2; ++kf)
#pragma unroll
      for (int vf = 0; vf < 2; ++vf)
#pragma unroll
        for (int q = 0; q < 4; ++q) acc[kf][vf][q] *= ebL;
#pragma unroll
    for (int ts = 0; ts < 2; ++ts) {
      bf16x8 aK[2], bZ[2];
#pragma unroll
      for (int kf = 0; kf < 2; ++kf)
        aK[kf] = *(const bf16x8*)(khatT16 + (cb * KK + wq * 32 + kf * 16 + lr) * CL + ts * 32 + lg * 8);
#pragma unroll
      for (int vf = 0; vf < 2; ++vf) {
        int v = vf * 16 + lr;
        bZ[vf] = *(const bf16x8*)((const char*)Zl + v * 128 + (((ts * 32 + lg * 8) * 2) ^ ((v & 7) << 4)));
      }
#pragma unroll
      for (int kf = 0; kf < 2; ++kf)
#pragma unroll
        for (int vf = 0; vf < 2; ++vf)
          acc[kf][vf] = __builtin_amdgcn_mfma_f32_16x16x32_bf16(aK[kf], bZ[vf], acc[kf][vf], 0, 0, 0);
    }
  }
}

// Pass 3: o = e^{b_t} q^T S0 + P Z (MFMA) + fused gated RMSNorm -> ovd bf16.
__global__ __launch_bounds__(256, 1)
void k_chunk3(const bf16_t* __restrict__ qb16, const bf16_t* __restrict__ kb16,
              const bf16_t* __restrict__ Zt, const bf16_t* __restrict__ states,
              const float* __restrict__ bcum, const float* __restrict__ fgate,
              const float* __restrict__ onorm_w, bf16_t* __restrict__ ovd) {
  __shared__ __align__(16) bf16_t qs[64 * 128];   // [t][k] swizzled via pre-XOR source
  __shared__ __align__(16) bf16_t ksh[64 * 128];
  __shared__ __align__(16) bf16_t Pl[64 * 64];    // [t][s] swizzled
  __shared__ float bcs[64];
  __shared__ float sred[4][64];

  int tid = threadIdx.x;
  int c = blockIdx.x, bh = blockIdx.y;
  int b = bh / HH, h = bh % HH;
  int r0 = b * TT + c * CL;
  size_t cb = (size_t)bh * NC + c;
  int wq = tid >> 6, l = tid & 63;
  int lr = l & 15, lg = l >> 4;

  if (tid < 64) bcs[tid] = bcum[cb * CL + tid];
#pragma unroll
  for (int it = 0; it < 4; ++it) {
    int idx = it * 256 + tid;
    int t = idx >> 4, p = idx & 15;
    int kslot = p ^ (t & 7);
    gload_lds16(qb16 + (size_t)(r0 + t) * KD + h * KK + kslot * 8,
                qs + (size_t)(it * 256 + wq * 64) * 8);
    gload_lds16(kb16 + (size_t)(r0 + t) * KD + h * KK + kslot * 8,
                ksh + (size_t)(it * 256 + wq * 64) * 8);
  }
  __syncthreads();

  // P = mask(q k^T) * e^{b_t-b_s}; wave wq covers t rows wq*16..+15
  f32x4 pacc[4];
#pragma unroll
  for (int sf = 0; sf < 4; ++sf) pacc[sf] = (f32x4){0.f, 0.f, 0.f, 0.f};
#pragma unroll
  for (int ks_ = 0; ks_ < 4; ++ks_) {
    int trow = wq * 16 + lr;
    bf16x8 aQ = *(const bf16x8*)((const char*)qs + trow * 256 + (((ks_ * 4 + lg) * 16) ^ ((trow & 7) << 4)));
#pragma unroll
    for (int sf = 0; sf < 4; ++sf) {
      int srow = sf * 16 + lr;
      bf16x8 bK = *(const bf16x8*)((const char*)ksh + srow * 256 + (((ks_ * 4 + lg) * 16) ^ ((srow & 7) << 4)));
      pacc[sf] = __builtin_amdgcn_mfma_f32_16x16x32_bf16(aQ, bK, pacc[sf], 0, 0, 0);
    }
  }
#pragma unroll
  for (int sf = 0; sf < 4; ++sf)
#pragma unroll
    for (int q = 0; q < 4; ++q) {
      int t = wq * 16 + lg * 4 + q;
      int s = sf * 16 + lr;
      float val = (s <= t) ? pacc[sf][q] * __expf(bcs[t] - bcs[s]) : 0.f;
      *(bf16_t*)((char*)Pl + t * 128 + ((s * 2) ^ ((t & 7) << 4))) = (bf16_t)val;
    }
  __syncthreads();

  // O: wave wq covers v cols wq*64..+63; oacc = qhat*S0^T + P*Zt
  f32x4 oacc[4][4];
#pragma unroll
  for (int ti = 0; ti < 4; ++ti)
#pragma unroll
    for (int vj = 0; vj < 4; ++vj) oacc[ti][vj] = (f32x4){0.f, 0.f, 0.f, 0.f};

#pragma unroll
  for (int ks_ = 0; ks_ < 4; ++ks_) {
    bf16x8 aQ[4];
#pragma unroll
    for (int ti = 0; ti < 4; ++ti) {
      int t = ti * 16 + lr;
      union { bf16x8 v; bf16_t e[8]; } u;
      u.v = *(const bf16x8*)((const char*)qs + t * 256 + (((ks_ * 4 + lg) * 16) ^ ((t & 7) << 4)));
      float eb = __expf(bcs[t]);
#pragma unroll
      for (int e = 0; e < 8; ++e) u.e[e] = (bf16_t)((float)u.e[e] * eb);
      aQ[ti] = u.v;
    }
#pragma unroll
    for (int vj = 0; vj < 4; ++vj) {
      int vrow = wq * 64 + vj * 16 + lr;
      bf16x8 bS = *(const bf16x8*)(states + ((size_t)cb * 256 + vrow) * 128 + ks_ * 32 + lg * 8);
#pragma unroll
      for (int ti = 0; ti < 4; ++ti)
        oacc[ti][vj] = __builtin_amdgcn_mfma_f32_16x16x32_bf16(aQ[ti], bS, oacc[ti][vj], 0, 0, 0);
    }
  }
#pragma unroll
  for (int ts = 0; ts < 2; ++ts) {
    bf16x8 aP[4];
#pragma unroll
    for (int ti = 0; ti < 4; ++ti) {
      int t = ti * 16 + lr;
      aP[ti] = *(const bf16x8*)((const char*)Pl + t * 128 + (((ts * 4 + lg) * 16) ^ ((t & 7) << 4)));
    }
#pragma unroll
    for (int vj = 0; vj < 4; ++vj) {
      int vrow = wq * 64 + vj * 16 + lr;
      bf16x8 bZ = *(const bf16x8*)(Zt + ((size_t)cb * 256 + vrow) * 64 + ts * 32 + lg * 8);
#pragma unroll
      for (int ti = 0; ti < 4; ++ti)
        oacc[ti][vj] = __builtin_amdgcn_mfma_f32_16x16x32_bf16(aP[ti], bZ, oacc[ti][vj], 0, 0, 0);
    }
  }

  // ---- fused gated RMSNorm ----
  float sum2[4][4];
#pragma unroll
  for (int ti = 0; ti < 4; ++ti)
#pragma unroll
    for (int q = 0; q < 4; ++q) {
      float s = 0.f;
#pragma unroll
      for (int vj = 0; vj < 4; ++vj) s += oacc[ti][vj][q] * oacc[ti][vj][q];
      sum2[ti][q] = s;
    }
#pragma unroll
  for (int mk = 1; mk < 16; mk <<= 1)
#pragma unroll
    for (int ti = 0; ti < 4; ++ti)
#pragma unroll
      for (int q = 0; q < 4; ++q)
        sum2[ti][q] += __shfl_xor(sum2[ti][q], mk, 64);
  if (lr == 0) {
#pragma unroll
    for (int ti = 0; ti < 4; ++ti)
#pragma unroll
      for (int q = 0; q < 4; ++q)
        sred[wq][ti * 16 + lg * 4 + q] = sum2[ti][q];
  }
  __syncthreads();

  float onv[4];
#pragma unroll
  for (int vj = 0; vj < 4; ++vj) onv[vj] = onorm_w[wq * 64 + vj * 16 + lr];
#pragma unroll
  for (int ti = 0; ti < 4; ++ti)
#pragma unroll
    for (int q = 0; q < 4; ++q) {
      int t = ti * 16 + lg * 4 + q;
      float tot = sred[0][t] + sred[1][t] + sred[2][t] + sred[3][t];
      float rn = rsqrtf(tot * (1.f / VV) + 1e-5f);
#pragma unroll
      for (int vj = 0; vj < 4; ++vj) {
        int v = wq * 64 + vj * 16 + lr;
        float gate = fgate[(size_t)(r0 + t) * VD + h * VV + v];
        float y = oacc[ti][vj][q] * rn * onv[vj] * (gate / (1.f + expf(-gate)));
        ovd[(size_t)(r0 + t) * VD + h * VV + v] = (bf16_t)y;
      }
    }
}

extern "C" void kernel_launch(void* const* d_in, const int* in_sizes, int n_in,
                              void* d_out, int out_size, void* d_ws, size_t ws_size,
                              hipStream_t stream) {
  const float* hidden = (const float*)d_in[0];
  const float* Wq = (const float*)d_in[1];
  const float* Wk = (const float*)d_in[2];
  const float* Wv = (const float*)d_in[3];
  const float* Wa = (const float*)d_in[4];
  const float* Wb = (const float*)d_in[5];
  const float* A_log = (const float*)d_in[6];
  const float* dt_bias = (const float*)d_in[7];
  const float* qconv = (const float*)d_in[8];
  const float* kconv = (const float*)d_in[9];
  const float* vconv = (const float*)d_in[10];
  const float* Wg = (const float*)d_in[11];
  const float* onorm = (const float*)d_in[12];
  const float* Wo = (const float*)d_in[13];
  float* out = (float*)d_out;

  char* ws = (char*)d_ws;
  size_t off = 0;
  auto alloc = [&](size_t bytes) {
    void* p = ws + off;
    off += (bytes + 255) & ~(size_t)255;
    return p;
  };
  const int M = BB * TT;  // 2048
  bf16_t* hbf   = (bf16_t*)alloc((size_t)M * CC * 2);       // aliased by Wn16/khatT16 later
  bf16_t* WcatT = (bf16_t*)alloc((size_t)NCAT * CC * 2);
  bf16_t* WoT   = (bf16_t*)alloc((size_t)CC * VD * 2);
  float*  fqkv  = (float*) alloc((size_t)M * NQKV * 4);     // aliased by states later
  float*  fgate = (float*) alloc((size_t)M * VD * 4);
  float*  kn    = (float*) alloc((size_t)M * KD * 4);       // aliased by Zt later
  float*  vn    = (float*) alloc((size_t)M * VD * 4);       // becomes Dv in pass 1
  float*  gdec  = (float*) alloc((size_t)M * HH * 4);
  float*  beta  = (float*) alloc((size_t)M * HH * 4);
  bf16_t* ovd   = (bf16_t*)alloc((size_t)M * VD * 2);
  bf16_t* qb16  = (bf16_t*)alloc((size_t)M * KD * 2);
  bf16_t* kb16  = (bf16_t*)alloc((size_t)M * KD * 2);
  float*  bcum  = (float*) alloc((size_t)12 * NC * CL * 4);

  // aliases (stream-ordered lifetime separation):
  bf16_t* Wn16    = (bf16_t*)hbf;                     // 12*16*64*128 bf16 = 3.15MB
  bf16_t* khatT16 = Wn16 + (size_t)12 * NC * CL * KK; // +3.15MB (hbf is 8.4MB)
  bf16_t* states  = (bf16_t*)fqkv;                    // 12*16*256*128 bf16 = 12.6MB
  bf16_t* Zt      = (bf16_t*)kn;                      // 12*16*256*64 bf16 = 6.3MB

  // pre-pass
  k_cvt_bf16<<<(M * CC / 4 + 255) / 256, 256, 0, stream>>>(hidden, hbf, M * CC);
  k_transpose_cvt<<<dim3(KD / 32, CC / 32), dim3(32, 8), 0, stream>>>(Wq, WcatT, CC, KD);
  k_transpose_cvt<<<dim3(KD / 32, CC / 32), dim3(32, 8), 0, stream>>>(Wk, WcatT + (size_t)768 * CC, CC, KD);
  k_transpose_cvt<<<dim3(VD / 32, CC / 32), dim3(32, 8), 0, stream>>>(Wv, WcatT + (size_t)1536 * CC, CC, VD);
  k_transpose_cvt<<<dim3(VD / 32, CC / 32), dim3(32, 8), 0, stream>>>(Wg, WcatT + (size_t)3072 * CC, CC, VD);
  k_transpose_cvt<<<dim3(CC / 32, VD / 32), dim3(32, 8), 0, stream>>>(Wo, WoT, VD, CC);

  // projections
  k_gemm_bt<<<dim3(NQKV / 128, M / 128), 256, 0, stream>>>(hbf, WcatT, fqkv, M, NQKV, CC);
  k_gemm_bt<<<dim3(VD / 128, M / 128), 256, 0, stream>>>(hbf, WcatT + (size_t)3072 * CC, fgate, M, VD, CC);

  // beta / g
  k_ab<<<M, 64, 0, stream>>>(hidden, Wa, Wb, A_log, dt_bias, gdec, beta);

  // conv + silu (+norm for q,k)
  k_conv_silu<<<dim3(M, HH), 128, 0, stream>>>(fqkv, NQKV, 0, qconv, nullptr, qb16, KD, 1);
  k_conv_silu<<<dim3(M, HH), 128, 0, stream>>>(fqkv, NQKV, 768, kconv, nullptr, kb16, KD, 1);
  k_conv_silu<<<dim3(M, HH), 256, 0, stream>>>(fqkv, NQKV, 1536, vconv, vn, nullptr, VD, 0);

  // chunked gated delta rule (hbf dead -> Wn16/khatT16; fqkv dead -> states; kn dead -> Zt)
  k_chunk1<<<dim3(NC, 12, 2), 256, 0, stream>>>(kb16, vn, gdec, beta, Wn16, khatT16, bcum);
  k_chunk2<<<dim3(8, 12), 256, 0, stream>>>(vn, Wn16, khatT16, bcum, states, Zt);
  k_chunk3<<<dim3(NC, 12), 256, 0, stream>>>(qb16, kb16, Zt, states, bcum, fgate, onorm, ovd);

  // output projection
  k_gemm_bt<<<dim3(CC / 128, M / 128), 256, 0, stream>>>(ovd, WoT, out, M, CC, VD);
}